// Round 4
// baseline (622.997 us; speedup 1.0000x reference)
//
#include <hip/hip_runtime.h>
#include <math.h>

#define BB 1024
#define LL 40
#define RR 1024

using short8 = __attribute__((ext_vector_type(8))) short;
using us8    = __attribute__((ext_vector_type(8))) unsigned short;
using f32x4  = __attribute__((ext_vector_type(4))) float;

__device__ __forceinline__ ushort f2bf(float f) {
    union { float f; unsigned u; } a; a.f = f;
    unsigned r = a.u + 0x7fffu + ((a.u >> 16) & 1u);  // RNE
    return (ushort)(r >> 16);
}
__device__ __forceinline__ float bf2f(ushort u) {
    union { unsigned u; float f; } a; a.u = ((unsigned)u) << 16;
    return a.f;
}
__device__ __forceinline__ float ftanh(float x) {
    float cx = fminf(fmaxf(x, -15.f), 15.f);
    float e = __expf(2.f * cx);
    return (e - 1.f) / (e + 1.f);
}
__device__ __forceinline__ float fsigmoid(float x) {
    float cx = fminf(fmaxf(x, -30.f), 30.f);
    return 1.f / (1.f + __expf(-cx));
}

// ---------------------------------------------------------------------------
struct CP3 { const float* in[3]; ushort* out[3]; };
__global__ __launch_bounds__(256) void conv_bf16_batch3_kernel(CP3 p, int n8)
{
    const int z = blockIdx.y;
    const int i = blockIdx.x * 256 + threadIdx.x;
    if (i >= n8) return;
    const float4* s4 = (const float4*)(p.in[z] + (size_t)i * 8);
    float4 x = s4[0], y = s4[1];
    us8 v;
    v[0] = f2bf(x.x); v[1] = f2bf(x.y); v[2] = f2bf(x.z); v[3] = f2bf(x.w);
    v[4] = f2bf(y.x); v[5] = f2bf(y.y); v[6] = f2bf(y.z); v[7] = f2bf(y.w);
    ((us8*)p.out[z])[i] = v;
}

// Transpose + convert: in fp32 [K=1024][N] -> out bf16 [N][1024].
struct TP6 { const float* in[6]; ushort* out[6]; int N[6]; };
__global__ __launch_bounds__(256) void transpose_conv_kernel(TP6 p)
{
    const int z = blockIdx.z;
    const int Nn = p.N[z];
    const int n0 = blockIdx.x * 64;
    if (n0 >= Nn) return;
    const int k0 = blockIdx.y * 64;
    const float* in = p.in[z];
    ushort* out = p.out[z];

    __shared__ float tile[64][65];
    const int t = threadIdx.x;
    const int tx = t & 63, ty = t >> 6;
#pragma unroll
    for (int r = 0; r < 16; ++r) {
        const int row = ty * 16 + r;
        tile[row][tx] = in[(size_t)(k0 + row) * Nn + n0 + tx];
    }
    __syncthreads();
    const int n = t >> 2, kq = t & 3;
    us8 v0, v1;
#pragma unroll
    for (int j = 0; j < 8; ++j) v0[j] = f2bf(tile[kq * 16 + j][n]);
#pragma unroll
    for (int j = 0; j < 8; ++j) v1[j] = f2bf(tile[kq * 16 + 8 + j][n]);
    ushort* op = out + (size_t)(n0 + n) * 1024 + k0 + kq * 16;
    *(us8*)op = v0;
    *((us8*)op + 1) = v1;
}

// ---------------------------------------------------------------------------
// Double-buffered BF16 MFMA GEMM. One barrier per K-step (BK=64).
// A_p: [M][1024] bf16 (or fp32 if CVTA, converted during staging).
// W_p: [N][1024] bf16 (pre-transposed). C = sum_p A_p @ W_p^T.
// Geometry: block BM x BN, WMxWN waves (per-wave BM/WM x BN/WN).
// Requires BM == BN == threads/2. EPI: 0 bias+store, 2 attn tanh-reduce,
// 3 split-K partial store.
// ---------------------------------------------------------------------------
template <int BM, int BN, int WM, int WN, bool CVTA, int NP, int EPI, int SK>
__global__ __launch_bounds__(WM * WN * 64, 2) void gemm_dbuf(
    const void* __restrict__ A0v, const void* __restrict__ A1v, const void* __restrict__ A2v,
    const ushort* __restrict__ W0, const ushort* __restrict__ W1, const ushort* __restrict__ W2,
    const float* __restrict__ b0, const float* __restrict__ b1, const float* __restrict__ b2,
    float* __restrict__ C, int M, int N,
    const float* __restrict__ hq, const float* __restrict__ bv2a,
    const float* __restrict__ Wa2w, float* __restrict__ epart)
{
    constexpr int PMW = BM / WM, PNW = BN / WN;
    constexpr int FM = PMW / 16, FN = PNW / 16;
    __shared__ ushort Alds[2][BM * 72];
    __shared__ ushort Blds[2][BN * 72];

    const int t = threadIdx.x, lane = t & 63, wave = t >> 6;
    const int wm = wave / WN, wn = wave % WN;

    int bx, by;
    if constexpr (EPI == 2) {
        // XCD-chunked bijective swizzle for nwg = 2*160 = 320 = 8*40
        const int lin = blockIdx.y * gridDim.x + blockIdx.x;
        const int swz = (lin & 7) * 40 + (lin >> 3);
        bx = swz & 1; by = swz >> 1;
    } else {
        bx = blockIdx.x; by = blockIdx.y;
    }
    const int m0 = by * BM, n0 = bx * BN;

    const int srow = t >> 1, skh = t & 1;
    const int soff = srow * 72 + skh * 32;

    f32x4 acc[FM][FN];
#pragma unroll
    for (int i = 0; i < FM; ++i)
#pragma unroll
        for (int j = 0; j < FN; ++j) acc[i][j] = (f32x4){0.f, 0.f, 0.f, 0.f};

    short8 ra[4]; float4 raf[8]; short8 rw[4];

    auto loadAB = [&](int s) {
        const int p  = (NP == 1) ? 0 : (s >> 4);
        const int k0 = (s & 15) << 6;
        if constexpr (CVTA) {
            const float* Ap = (const float*)((p == 0) ? A0v : ((p == 1) ? A1v : A2v));
            const float4* ag = (const float4*)(Ap + (size_t)(m0 + srow) * 1024 + k0 + skh * 32);
#pragma unroll
            for (int j = 0; j < 8; ++j) raf[j] = ag[j];
        } else {
            const ushort* Ap = (const ushort*)((p == 0) ? A0v : ((p == 1) ? A1v : A2v));
            const short8* ag = (const short8*)(Ap + (size_t)(m0 + srow) * 1024 + k0 + skh * 32);
#pragma unroll
            for (int j = 0; j < 4; ++j) ra[j] = ag[j];
        }
        const ushort* Wp = (p == 0) ? W0 : ((p == 1) ? W1 : W2);
        const short8* wg = (const short8*)(Wp + (size_t)(n0 + srow) * 1024 + k0 + skh * 32);
#pragma unroll
        for (int j = 0; j < 4; ++j) rw[j] = wg[j];
    };

    auto stageTo = [&](int buf) {
        ushort* ad = &Alds[buf][soff];
        if constexpr (CVTA) {
#pragma unroll
            for (int q = 0; q < 4; ++q) {
                float4 x = raf[2 * q], y = raf[2 * q + 1];
                short8 v;
                v[0] = (short)f2bf(x.x); v[1] = (short)f2bf(x.y);
                v[2] = (short)f2bf(x.z); v[3] = (short)f2bf(x.w);
                v[4] = (short)f2bf(y.x); v[5] = (short)f2bf(y.y);
                v[6] = (short)f2bf(y.z); v[7] = (short)f2bf(y.w);
                *(short8*)(ad + q * 8) = v;
            }
        } else {
#pragma unroll
            for (int j = 0; j < 4; ++j) *(short8*)(ad + j * 8) = ra[j];
        }
        ushort* bd = &Blds[buf][soff];
#pragma unroll
        for (int j = 0; j < 4; ++j) *(short8*)(bd + j * 8) = rw[j];
    };

    const int total = NP * 16;
    const int per   = total / SK;
    const int s0    = blockIdx.z * per;
    const int sEnd  = s0 + per;

    loadAB(s0);
    stageTo(0);
    __syncthreads();

    int cur = 0;
    for (int s = s0; s < sEnd; ++s) {
        if (s + 1 < sEnd) loadAB(s + 1);     // issue next-tile global loads early
#pragma unroll
        for (int ks = 0; ks < 2; ++ks) {
            short8 aF[FM], bF[FN];
#pragma unroll
            for (int mi = 0; mi < FM; ++mi)
                aF[mi] = *(const short8*)&Alds[cur][(wm * PMW + mi * 16 + (lane & 15)) * 72 + ks * 32 + (lane >> 4) * 8];
#pragma unroll
            for (int ni = 0; ni < FN; ++ni)
                bF[ni] = *(const short8*)&Blds[cur][(wn * PNW + ni * 16 + (lane & 15)) * 72 + ks * 32 + (lane >> 4) * 8];
            __builtin_amdgcn_s_setprio(1);
#pragma unroll
            for (int mi = 0; mi < FM; ++mi)
#pragma unroll
                for (int ni = 0; ni < FN; ++ni)
                    acc[mi][ni] = __builtin_amdgcn_mfma_f32_16x16x32_bf16(aF[mi], bF[ni], acc[mi][ni], 0, 0, 0);
            __builtin_amdgcn_s_setprio(0);
        }
        if (s + 1 < sEnd) stageTo(cur ^ 1);
        __syncthreads();
        cur ^= 1;
    }

    if constexpr (EPI == 0) {
#pragma unroll
        for (int ni = 0; ni < FN; ++ni) {
            const int col = n0 + wn * PNW + ni * 16 + (lane & 15);
            float bs = b0[col];
            if (NP > 1) bs += b1[col];
            if (NP > 2) bs += b2[col];
#pragma unroll
            for (int mi = 0; mi < FM; ++mi) {
                const int row = m0 + wm * PMW + mi * 16 + ((lane >> 4) << 2);
#pragma unroll
                for (int r = 0; r < 4; ++r)
                    C[(size_t)(row + r) * N + col] = acc[mi][ni][r] + bs;
            }
        }
    } else if constexpr (EPI == 3) {
        float* Cz = C + (size_t)blockIdx.z * M * N;
#pragma unroll
        for (int ni = 0; ni < FN; ++ni) {
            const int col = n0 + wn * PNW + ni * 16 + (lane & 15);
#pragma unroll
            for (int mi = 0; mi < FM; ++mi) {
                const int row = m0 + wm * PMW + mi * 16 + ((lane >> 4) << 2);
#pragma unroll
                for (int r = 0; r < 4; ++r)
                    Cz[(size_t)(row + r) * N + col] = acc[mi][ni][r];
            }
        }
    } else if constexpr (EPI == 2) {
        __syncthreads();                       // Alds no longer needed; alias as red
        float* red = (float*)&Alds[0][0];      // [BM][WN]
        float wa[FN], bv[FN];
        int coln[FN];
#pragma unroll
        for (int ni = 0; ni < FN; ++ni) {
            coln[ni] = n0 + wn * PNW + ni * 16 + (lane & 15);
            wa[ni] = Wa2w[coln[ni]];
            bv[ni] = bv2a[coln[ni]];
        }
#pragma unroll
        for (int mi = 0; mi < FM; ++mi) {
            const int rowl = wm * PMW + mi * 16 + ((lane >> 4) << 2);
#pragma unroll
            for (int r = 0; r < 4; ++r) {
                const int row = m0 + rowl + r;
                const int b = row / LL;
                float v = 0.f;
#pragma unroll
                for (int ni = 0; ni < FN; ++ni) {
                    float x = acc[mi][ni][r] + hq[(size_t)b * 512 + coln[ni]] + bv[ni];
                    v += ftanh(x) * wa[ni];
                }
                v += __shfl_xor(v, 1);
                v += __shfl_xor(v, 2);
                v += __shfl_xor(v, 4);
                v += __shfl_xor(v, 8);
                if ((lane & 15) == 0) red[(rowl + r) * WN + wn] = v;
            }
        }
        __syncthreads();
        if (t < BM) {
            float s = 0.f;
#pragma unroll
            for (int q = 0; q < WN; ++q) s += red[t * WN + q];
            epart[(size_t)(m0 + t) * 2 + bx] = s;
        }
    }
}

// ---------------------------------------------------------------------------
__global__ __launch_bounds__(256) void reduce_hq_kernel(
    const float* __restrict__ part, const float* __restrict__ bias, float* __restrict__ hq)
{
    const int i = blockIdx.x * 256 + threadIdx.x;   // < 1024*512
    float s = bias[i & 511];
#pragma unroll
    for (int z = 0; z < 8; ++z) s += part[(size_t)z * 524288 + i];
    hq[i] = s;
}

__global__ __launch_bounds__(256) void reduce_gate_kernel(
    const float* __restrict__ part, const float* __restrict__ bias,
    const float* __restrict__ pos, ushort* __restrict__ gpb)
{
    const int i = blockIdx.x * 256 + threadIdx.x;   // < 1024*1024
    float s = bias[i & 1023];
#pragma unroll
    for (int z = 0; z < 4; ++z) s += part[(size_t)z * 1048576 + i];
    const float g = fmaxf(s, 0.f);
    gpb[i] = f2bf(g * pos[i] + pos[i]);
}

// ---------------------------------------------------------------------------
// Per-batch softmax over L + weighted sum over fp32 V. Writes bf16 af.
// ---------------------------------------------------------------------------
__global__ __launch_bounds__(256) void softmax_af_kernel(
    const float* __restrict__ epart, const float* __restrict__ V,
    const float* __restrict__ ba2w, ushort* __restrict__ afb)
{
    const int b = blockIdx.x;
    const int tid = threadIdx.x;
    __shared__ float e_raw[LL];
    __shared__ float e_exp[LL];

    if (tid < LL) {
        const float* ep = &epart[(size_t)(b * LL + tid) * 2];
        e_raw[tid] = ba2w[0] + ep[0] + ep[1];
    }
    __syncthreads();
    float mx = -1e30f;
#pragma unroll
    for (int l = 0; l < LL; ++l) mx = fmaxf(mx, e_raw[l]);
    if (tid < LL) e_exp[tid] = __expf(e_raw[tid] - mx);
    __syncthreads();
    float sum = 0.f;
#pragma unroll
    for (int l = 0; l < LL; ++l) sum += e_exp[l];
    const float inv = 1.f / sum;

    const int r4 = tid * 4;
    const float* vp = &V[(size_t)b * LL * RR + r4];
    float a0 = 0.f, a1 = 0.f, a2 = 0.f, a3 = 0.f;
#pragma unroll 8
    for (int l = 0; l < LL; ++l) {
        float4 v = *(const float4*)&vp[(size_t)l * RR];
        const float w = e_exp[l];
        a0 += w * v.x; a1 += w * v.y; a2 += w * v.z; a3 += w * v.w;
    }
    ushort* op = &afb[(size_t)b * RR + r4];
    op[0] = f2bf(a0 * inv); op[1] = f2bf(a1 * inv);
    op[2] = f2bf(a2 * inv); op[3] = f2bf(a3 * inv);
}

__global__ __launch_bounds__(256) void lstm_finish_kernel(
    const float* __restrict__ s, const float* __restrict__ c_in,
    const float* __restrict__ h_in, const float* __restrict__ mask,
    float* __restrict__ h_out, float* __restrict__ h_out2,
    float* __restrict__ c_out, ushort* __restrict__ h_bf)
{
    const int i = blockIdx.x * 256 + threadIdx.x;  // [0, B*R)
    const int b = i >> 10;
    const int r = i & 1023;
    const float* sb = &s[(size_t)b * 4 * RR];
    const float ig = fsigmoid(sb[r]);
    const float fg = fsigmoid(sb[RR + r]);
    const float og = fsigmoid(sb[2 * RR + r]);
    const float g  = ftanh(sb[3 * RR + r]);
    const float m = mask[b];
    const float c = c_in[i];
    float cn = fg * c + ig * g;
    cn = cn * m + c * (1.f - m);
    const float h = h_in[i];
    float hn = og * ftanh(cn);
    hn = hn * m + h * (1.f - m);
    h_out[i] = hn;
    if (h_out2) h_out2[i] = hn;
    c_out[i] = cn;
    if (h_bf) h_bf[i] = f2bf(hn);
}

extern "C" void kernel_launch(void* const* d_in, const int* in_sizes, int n_in,
                              void* d_out, int out_size, void* d_ws, size_t ws_size,
                              hipStream_t stream) {
    const float* xt   = (const float*)d_in[0];
    const float* mask = (const float*)d_in[1];
    const float* V    = (const float*)d_in[2];
    const float* pos  = (const float*)d_in[3];
    const float* h1   = (const float*)d_in[4];
    const float* c1   = (const float*)d_in[5];
    const float* h2   = (const float*)d_in[6];
    const float* c2   = (const float*)d_in[7];
    const float* Wg   = (const float*)d_in[8];
    const float* bg   = (const float*)d_in[9];
    const float* Wi1  = (const float*)d_in[10];
    const float* bi1  = (const float*)d_in[11];
    const float* Wa1  = (const float*)d_in[12];
    const float* ba1  = (const float*)d_in[13];
    const float* Wh1  = (const float*)d_in[14];
    const float* bh1  = (const float*)d_in[15];
    const float* Wi2  = (const float*)d_in[16];
    const float* bi2  = (const float*)d_in[17];
    const float* Wa2  = (const float*)d_in[18];
    const float* ba2  = (const float*)d_in[19];
    const float* Wh2  = (const float*)d_in[20];
    const float* bh2  = (const float*)d_in[21];
    const float* Wv2a = (const float*)d_in[22];
    const float* bv2a = (const float*)d_in[23];
    const float* Wh2a = (const float*)d_in[24];
    const float* bh2a = (const float*)d_in[25];
    const float* Wa2w = (const float*)d_in[26];
    const float* ba2w = (const float*)d_in[27];

    float* out = (float*)d_out;
    float* out2  = out;
    float* out1  = out + (size_t)BB * RR;
    float* c1n   = out + 2 * (size_t)BB * RR;
    float* out2b = out + 3 * (size_t)BB * RR;
    float* c2n   = out + 4 * (size_t)BB * RR;

    // ---- workspace: bf16 region then fp32 region ----
    ushort* wsu = (ushort*)d_ws;
    size_t o = 0;
    ushort* Wh2aT0 = wsu + o; o += (size_t)512 * 1024;
    ushort* Wh2aT1 = wsu + o; o += (size_t)512 * 1024;
    ushort* WgT    = wsu + o; o += (size_t)1024 * 1024;
    ushort* Wv2aT  = wsu + o; o += (size_t)512 * 1024;
    ushort* Wi1T   = wsu + o; o += (size_t)4096 * 1024;
    ushort* Wa1T   = wsu + o; o += (size_t)4096 * 1024;
    ushort* Wh1T   = wsu + o; o += (size_t)4096 * 1024;
    ushort* Wi2T   = wsu + o; o += (size_t)4096 * 1024;
    ushort* Wa2T   = wsu + o; o += (size_t)4096 * 1024;
    ushort* Wh2T   = wsu + o; o += (size_t)4096 * 1024;
    ushort* xtb    = wsu + o; o += (size_t)1024 * 1024;
    ushort* h1b    = wsu + o; o += (size_t)1024 * 1024;
    ushort* h2b    = wsu + o; o += (size_t)1024 * 1024;
    ushort* gpb    = wsu + o; o += (size_t)1024 * 1024;
    ushort* afb    = wsu + o; o += (size_t)1024 * 1024;
    ushort* out1b  = wsu + o; o += (size_t)1024 * 1024;
    float* wsf   = (float*)(wsu + o);
    float* hqf   = wsf;                    // 1024*512
    float* epart = hqf + 524288;           // 40960*2
    float* partK = epart + 81920;          // 8*1024*512 (hq) / 4*1024*1024 (gate)
    float* sbuf  = partK + 4194304;        // 1024*4096

    const dim3 blk(256);
    const dim3 blk8(512);

    // ---- conversion / transpose passes ----
    {
        CP3 p; p.in[0] = xt; p.in[1] = h1; p.in[2] = h2;
        p.out[0] = xtb; p.out[1] = h1b; p.out[2] = h2b;
        conv_bf16_batch3_kernel<<<dim3(512, 3), blk, 0, stream>>>(p, 131072);
    }
    {
        TP6 p;
        p.in[0] = Wi1; p.in[1] = Wa1; p.in[2] = Wh1;
        p.in[3] = Wi2; p.in[4] = Wa2; p.in[5] = Wh2;
        p.out[0] = Wi1T; p.out[1] = Wa1T; p.out[2] = Wh1T;
        p.out[3] = Wi2T; p.out[4] = Wa2T; p.out[5] = Wh2T;
        for (int z = 0; z < 6; ++z) p.N[z] = 4096;
        transpose_conv_kernel<<<dim3(64, 16, 6), blk, 0, stream>>>(p);
    }
    {
        TP6 p;
        p.in[0] = Wh2a; p.in[1] = Wh2a + (size_t)1024 * 512;
        p.in[2] = Wg;   p.in[3] = Wv2a;
        p.out[0] = Wh2aT0; p.out[1] = Wh2aT1; p.out[2] = WgT; p.out[3] = Wv2aT;
        p.N[0] = 512; p.N[1] = 512; p.N[2] = 1024; p.N[3] = 512;
        p.in[4] = nullptr; p.in[5] = nullptr; p.out[4] = nullptr; p.out[5] = nullptr;
        p.N[4] = 0; p.N[5] = 0;
        transpose_conv_kernel<<<dim3(16, 16, 4), blk, 0, stream>>>(p);
    }

    // ---- hq = [h1,h2] @ Wh2a + bh2a (split-K x8 + reduce) ----
    gemm_dbuf<128, 128, 2, 2, false, 2, 3, 8><<<dim3(4, 8, 8), blk, 0, stream>>>(
        h1b, h2b, nullptr, Wh2aT0, Wh2aT1, nullptr,
        nullptr, nullptr, nullptr, partK, 1024, 512, nullptr, nullptr, nullptr, nullptr);
    reduce_hq_kernel<<<dim3(2048), blk, 0, stream>>>(partK, bh2a, hqf);

    // ---- gate: xt @ Wg (split-K x4), fused relu*pos+pos -> bf16 ----
    gemm_dbuf<128, 128, 2, 2, false, 1, 3, 4><<<dim3(8, 8, 4), blk, 0, stream>>>(
        xtb, nullptr, nullptr, WgT, nullptr, nullptr,
        nullptr, nullptr, nullptr, partK, 1024, 1024, nullptr, nullptr, nullptr, nullptr);
    reduce_gate_kernel<<<dim3(4096), blk, 0, stream>>>(partK, bg, pos, gpb);

    // ---- attention scores: fp32 V (cvt in staging) @ Wv2a, tanh-reduce ----
    gemm_dbuf<256, 256, 2, 4, true, 1, 2, 1><<<dim3(2, 160, 1), blk8, 0, stream>>>(
        V, nullptr, nullptr, Wv2aT, nullptr, nullptr,
        nullptr, nullptr, nullptr, nullptr, 40960, 512, hqf, bv2a, Wa2w, epart);
    softmax_af_kernel<<<dim3(BB), blk, 0, stream>>>(epart, V, ba2w, afb);

    // ---- LSTM layer 1 ----
    gemm_dbuf<128, 128, 2, 2, false, 3, 0, 1><<<dim3(32, 8, 1), blk, 0, stream>>>(
        xtb, gpb, h1b, Wi1T, Wa1T, Wh1T, bi1, ba1, bh1,
        sbuf, 1024, 4096, nullptr, nullptr, nullptr, nullptr);
    lstm_finish_kernel<<<dim3(4096), blk, 0, stream>>>(sbuf, c1, h1, mask, out1, nullptr, c1n, out1b);

    // ---- LSTM layer 2 ----
    gemm_dbuf<128, 128, 2, 2, false, 3, 0, 1><<<dim3(32, 8, 1), blk, 0, stream>>>(
        out1b, afb, h2b, Wi2T, Wa2T, Wh2T, bi2, ba2, bh2,
        sbuf, 1024, 4096, nullptr, nullptr, nullptr, nullptr);
    lstm_finish_kernel<<<dim3(4096), blk, 0, stream>>>(sbuf, c2, h2, mask, out2, out2b, c2n, nullptr);
}

// Round 5
// 617.367 us; speedup vs baseline: 1.0091x; 1.0091x over previous
//
#include <hip/hip_runtime.h>
#include <math.h>

#define BB 1024
#define LL 40
#define RR 1024

using short8 = __attribute__((ext_vector_type(8))) short;
using us8    = __attribute__((ext_vector_type(8))) unsigned short;
using f32x4  = __attribute__((ext_vector_type(4))) float;

__device__ __forceinline__ ushort f2bf(float f) {
    union { float f; unsigned u; } a; a.f = f;
    unsigned r = a.u + 0x7fffu + ((a.u >> 16) & 1u);  // RNE
    return (ushort)(r >> 16);
}
__device__ __forceinline__ float ftanh(float x) {
    float cx = fminf(fmaxf(x, -15.f), 15.f);
    float e = __expf(2.f * cx);
    return (e - 1.f) / (e + 1.f);
}
__device__ __forceinline__ float fsigmoid(float x) {
    float cx = fminf(fmaxf(x, -30.f), 30.f);
    return 1.f / (1.f + __expf(-cx));
}

// ---------------------------------------------------------------------------
struct CP3 { const float* in[3]; ushort* out[3]; };
__global__ __launch_bounds__(256) void conv_bf16_batch3_kernel(CP3 p, int n8)
{
    const int z = blockIdx.y;
    const int i = blockIdx.x * 256 + threadIdx.x;
    if (i >= n8) return;
    const float4* s4 = (const float4*)(p.in[z] + (size_t)i * 8);
    float4 x = s4[0], y = s4[1];
    us8 v;
    v[0] = f2bf(x.x); v[1] = f2bf(x.y); v[2] = f2bf(x.z); v[3] = f2bf(x.w);
    v[4] = f2bf(y.x); v[5] = f2bf(y.y); v[6] = f2bf(y.z); v[7] = f2bf(y.w);
    ((us8*)p.out[z])[i] = v;
}

// Transpose + convert: in fp32 [K=1024][N] -> out bf16 [N][1024].
struct TP6 { const float* in[6]; ushort* out[6]; int N[6]; };
__global__ __launch_bounds__(256) void transpose_conv_kernel(TP6 p)
{
    const int z = blockIdx.z;
    const int Nn = p.N[z];
    const int n0 = blockIdx.x * 64;
    if (n0 >= Nn) return;
    const int k0 = blockIdx.y * 64;
    const float* in = p.in[z];
    ushort* out = p.out[z];

    __shared__ float tile[64][65];
    const int t = threadIdx.x;
    const int tx = t & 63, ty = t >> 6;
#pragma unroll
    for (int r = 0; r < 16; ++r) {
        const int row = ty * 16 + r;
        tile[row][tx] = in[(size_t)(k0 + row) * Nn + n0 + tx];
    }
    __syncthreads();
    const int n = t >> 2, kq = t & 3;
    us8 v0, v1;
#pragma unroll
    for (int j = 0; j < 8; ++j) v0[j] = f2bf(tile[kq * 16 + j][n]);
#pragma unroll
    for (int j = 0; j < 8; ++j) v1[j] = f2bf(tile[kq * 16 + 8 + j][n]);
    ushort* op = out + (size_t)(n0 + n) * 1024 + k0 + kq * 16;
    *(us8*)op = v0;
    *((us8*)op + 1) = v1;
}

// ---------------------------------------------------------------------------
// BF16 MFMA GEMM, 128x128 tile, BK=64, 256 threads (4 waves, 2x2 of 64x64).
// A_p: bf16 [M][1024] row-major. W_p: bf16 [N][1024] (pre-transposed).
// C_z = partial of sum_p A_p @ W_p^T over this z's K-range (EPI=3 only).
// ---------------------------------------------------------------------------
template <int NP, int SK>
__global__ __launch_bounds__(256) void gemm_bf16(
    const ushort* __restrict__ A0, const ushort* __restrict__ A1, const ushort* __restrict__ A2,
    const ushort* __restrict__ W0, const ushort* __restrict__ W1, const ushort* __restrict__ W2,
    float* __restrict__ C, int M, int N)
{
    __shared__ ushort Alds[128 * 72];
    __shared__ ushort Blds[128 * 72];

    const int t = threadIdx.x;
    const int lane = t & 63;
    const int wave = t >> 6;
    const int wm = wave >> 1, wn = wave & 1;
    const int m0 = blockIdx.y * 128, n0 = blockIdx.x * 128;

    const int srow = t >> 1, skh = t & 1;      // staging: row 0..127, k-half
    const int soff = srow * 72 + skh * 32;

    f32x4 acc[4][4];
#pragma unroll
    for (int i = 0; i < 4; ++i)
#pragma unroll
        for (int j = 0; j < 4; ++j) acc[i][j] = (f32x4){0.f, 0.f, 0.f, 0.f};

    const int total = NP * 16;            // K-steps of 64
    const int per   = total / SK;
    const int s0    = blockIdx.z * per;
    const int sEnd  = s0 + per;

    short8 ra[4], rw[4];
    auto loadAB = [&](int s) {
        const int p  = (NP == 1) ? 0 : (s >> 4);
        const int k0 = (s & 15) << 6;
        const ushort* Ap = (p == 0) ? A0 : ((p == 1) ? A1 : A2);
        const ushort* Wp = (p == 0) ? W0 : ((p == 1) ? W1 : W2);
        const short8* ag = (const short8*)(Ap + (size_t)(m0 + srow) * 1024 + k0 + skh * 32);
        const short8* wg = (const short8*)(Wp + (size_t)(n0 + srow) * 1024 + k0 + skh * 32);
#pragma unroll
        for (int j = 0; j < 4; ++j) { ra[j] = ag[j]; rw[j] = wg[j]; }
    };

    loadAB(s0);

    for (int s = s0; s < sEnd; ++s) {
        __syncthreads();   // previous iteration's fragment reads done
#pragma unroll
        for (int j = 0; j < 4; ++j) {
            *(short8*)&Alds[soff + j * 8] = ra[j];
            *(short8*)&Blds[soff + j * 8] = rw[j];
        }
        __syncthreads();
        if (s + 1 < sEnd) loadAB(s + 1);   // prefetch next tile into regs
#pragma unroll
        for (int ks = 0; ks < 2; ++ks) {
            short8 aF[4], bF[4];
#pragma unroll
            for (int mi = 0; mi < 4; ++mi)
                aF[mi] = *(const short8*)&Alds[(wm * 64 + mi * 16 + (lane & 15)) * 72 + ks * 32 + (lane >> 4) * 8];
#pragma unroll
            for (int ni = 0; ni < 4; ++ni)
                bF[ni] = *(const short8*)&Blds[(wn * 64 + ni * 16 + (lane & 15)) * 72 + ks * 32 + (lane >> 4) * 8];
#pragma unroll
            for (int mi = 0; mi < 4; ++mi)
#pragma unroll
                for (int ni = 0; ni < 4; ++ni)
                    acc[mi][ni] = __builtin_amdgcn_mfma_f32_16x16x32_bf16(aF[mi], bF[ni], acc[mi][ni], 0, 0, 0);
        }
    }

    // EPI=3: split-K partial store
    float* Cz = C + (size_t)blockIdx.z * M * N;
#pragma unroll
    for (int ni = 0; ni < 4; ++ni) {
        const int col = n0 + wn * 64 + ni * 16 + (lane & 15);
#pragma unroll
        for (int mi = 0; mi < 4; ++mi) {
            const int row = m0 + wm * 64 + mi * 16 + ((lane >> 4) << 2);
#pragma unroll
            for (int r = 0; r < 4; ++r)
                Cz[(size_t)(row + r) * N + col] = acc[mi][ni][r];
        }
    }
}

// ---------------------------------------------------------------------------
// Fused attention: per block 80 V-rows (2 batches), full N=512.
// e = tanh(V@Wv2a + hq + bv2a) @ Wa2w + ba2w -> softmax over L=40 -> af = w.V
// 512 threads (8 waves). A = V fp32 (cvt in staging), B = Wv2aT bf16.
// ---------------------------------------------------------------------------
__global__ __launch_bounds__(512) void attn_fused_kernel(
    const float* __restrict__ V, const ushort* __restrict__ WT,
    const float* __restrict__ hq, const float* __restrict__ bv2a,
    const float* __restrict__ Wa2w, const float* __restrict__ ba2w,
    ushort* __restrict__ afb)
{
    __shared__ ushort Alds[80 * 40];    // [row][k] pad 40
    __shared__ ushort Blds[512 * 40];   // [col][k] pad 40

    const int t = threadIdx.x, lane = t & 63, wn = t >> 6;
    const int lin = blockIdx.x;
    const int blk = (lin & 7) * 64 + (lin >> 3);   // XCD-chunked, 512 = 8*64
    const int m0 = blk * 80;

    f32x4 acc[5][4];
#pragma unroll
    for (int i = 0; i < 5; ++i)
#pragma unroll
        for (int j = 0; j < 4; ++j) acc[i][j] = (f32x4){0.f, 0.f, 0.f, 0.f};

    const int arow = t >> 2, aq = t & 3;   // t<320: A staging

    float4 raf0, raf1;
    short8 rw[4];
    auto loadA = [&](int k0) {
        const float* ap = V + (size_t)(m0 + arow) * 1024 + k0 + aq * 8;
        raf0 = ((const float4*)ap)[0];
        raf1 = ((const float4*)ap)[1];
    };
    auto loadB = [&](int k0) {
        const short8* wp = (const short8*)(WT + (size_t)t * 1024 + k0);
#pragma unroll
        for (int j = 0; j < 4; ++j) rw[j] = wp[j];
    };

    if (t < 320) loadA(0);
    loadB(0);

    for (int s = 0; s < 32; ++s) {
        __syncthreads();
        if (t < 320) {
            short8 v;
            v[0] = (short)f2bf(raf0.x); v[1] = (short)f2bf(raf0.y);
            v[2] = (short)f2bf(raf0.z); v[3] = (short)f2bf(raf0.w);
            v[4] = (short)f2bf(raf1.x); v[5] = (short)f2bf(raf1.y);
            v[6] = (short)f2bf(raf1.z); v[7] = (short)f2bf(raf1.w);
            *(short8*)&Alds[arow * 40 + aq * 8] = v;
        }
#pragma unroll
        for (int j = 0; j < 4; ++j) *(short8*)&Blds[t * 40 + j * 8] = rw[j];
        __syncthreads();
        if (s + 1 < 32) {
            if (t < 320) loadA((s + 1) * 32);
            loadB((s + 1) * 32);
        }
        short8 aF[5], bF[4];
#pragma unroll
        for (int mi = 0; mi < 5; ++mi)
            aF[mi] = *(const short8*)&Alds[(mi * 16 + (lane & 15)) * 40 + (lane >> 4) * 8];
#pragma unroll
        for (int ni = 0; ni < 4; ++ni)
            bF[ni] = *(const short8*)&Blds[(wn * 64 + ni * 16 + (lane & 15)) * 40 + (lane >> 4) * 8];
        __builtin_amdgcn_s_setprio(1);
#pragma unroll
        for (int mi = 0; mi < 5; ++mi)
#pragma unroll
            for (int ni = 0; ni < 4; ++ni)
                acc[mi][ni] = __builtin_amdgcn_mfma_f32_16x16x32_bf16(aF[mi], bF[ni], acc[mi][ni], 0, 0, 0);
        __builtin_amdgcn_s_setprio(0);
    }

    // ---- epilogue: tanh-reduce -> e[80] -> softmax -> PV ----
    __syncthreads();
    float* red = (float*)Alds;          // [80][8]
    float wa[4], bv[4];
    int coln[4];
#pragma unroll
    for (int ni = 0; ni < 4; ++ni) {
        coln[ni] = wn * 64 + ni * 16 + (lane & 15);
        wa[ni] = Wa2w[coln[ni]];
        bv[ni] = bv2a[coln[ni]];
    }
#pragma unroll
    for (int mi = 0; mi < 5; ++mi) {
        const int rowb = mi * 16 + ((lane >> 4) << 2);
#pragma unroll
        for (int r = 0; r < 4; ++r) {
            const int row = rowb + r;                 // 0..79
            const int bg = 2 * blk + (row >= 40 ? 1 : 0);
            float v = 0.f;
#pragma unroll
            for (int ni = 0; ni < 4; ++ni)
                v += ftanh(acc[mi][ni][r] + hq[(size_t)bg * 512 + coln[ni]] + bv[ni]) * wa[ni];
            v += __shfl_xor(v, 1);
            v += __shfl_xor(v, 2);
            v += __shfl_xor(v, 4);
            v += __shfl_xor(v, 8);
            if ((lane & 15) == 0) red[row * 8 + wn] = v;
        }
    }
    __syncthreads();
    float* esm = (float*)Blds;          // [80]
    float* wsm = esm + 80;              // [80]
    if (t < 80) {
        float e = ba2w[0];
#pragma unroll
        for (int q = 0; q < 8; ++q) e += red[t * 8 + q];
        esm[t] = e;
    }
    __syncthreads();
    if (t < 80) {
        const int base = (t >= 40) ? 40 : 0;
        float mx = -1e30f;
#pragma unroll
        for (int l = 0; l < LL; ++l) mx = fmaxf(mx, esm[base + l]);
        float sum = 0.f;
#pragma unroll
        for (int l = 0; l < LL; ++l) sum += __expf(esm[base + l] - mx);
        wsm[t] = __expf(esm[t] - mx) / sum;
    }
    __syncthreads();
    // PV: 1024 cols, 2 per thread; V rows are L2-hot (just streamed above)
#pragma unroll
    for (int half = 0; half < 2; ++half) {
        const int col = t + half * 512;
        const float* vp = V + (size_t)m0 * 1024 + col;
        float a0 = 0.f, a1 = 0.f;
#pragma unroll 4
        for (int l = 0; l < LL; ++l) {
            a0 += wsm[l]      * vp[(size_t)l * 1024];
            a1 += wsm[40 + l] * vp[(size_t)(40 + l) * 1024];
        }
        afb[(size_t)(2 * blk) * 1024 + col]     = f2bf(a0);
        afb[(size_t)(2 * blk + 1) * 1024 + col] = f2bf(a1);
    }
}

// ---------------------------------------------------------------------------
__global__ __launch_bounds__(256) void reduce_hq_kernel(
    const float* __restrict__ part, const float* __restrict__ bias, float* __restrict__ hq)
{
    const int i = blockIdx.x * 256 + threadIdx.x;   // < 1024*512
    float s = bias[i & 511];
#pragma unroll
    for (int z = 0; z < 8; ++z) s += part[(size_t)z * 524288 + i];
    hq[i] = s;
}

__global__ __launch_bounds__(256) void reduce_gate_kernel(
    const float* __restrict__ part, const float* __restrict__ bias,
    const float* __restrict__ pos, ushort* __restrict__ gpb)
{
    const int i = blockIdx.x * 256 + threadIdx.x;   // < 1024*1024
    float s = bias[i & 1023];
#pragma unroll
    for (int z = 0; z < 4; ++z) s += part[(size_t)z * 1048576 + i];
    const float g = fmaxf(s, 0.f);
    gpb[i] = f2bf(g * pos[i] + pos[i]);
}

// ---------------------------------------------------------------------------
// LSTM epilogue: sum 2 split-K partials + 3 biases, gates, mask blend.
// ---------------------------------------------------------------------------
__global__ __launch_bounds__(256) void lstm_finish2_kernel(
    const float* __restrict__ part,
    const float* __restrict__ bi, const float* __restrict__ ba, const float* __restrict__ bh,
    const float* __restrict__ c_in, const float* __restrict__ h_in, const float* __restrict__ mask,
    float* __restrict__ h_out, float* __restrict__ h_out2,
    float* __restrict__ c_out, ushort* __restrict__ h_bf)
{
    const int i = blockIdx.x * 256 + threadIdx.x;  // [0, B*R)
    const int b = i >> 10;
    const int r = i & 1023;
    const float* p0 = part + (size_t)b * 4096;
    const float* p1 = p0 + 4194304;
    float sg[4];
#pragma unroll
    for (int g = 0; g < 4; ++g) {
        const int gr = g * 1024 + r;
        sg[g] = p0[gr] + p1[gr] + bi[gr] + ba[gr] + bh[gr];
    }
    const float ig = fsigmoid(sg[0]);
    const float fg = fsigmoid(sg[1]);
    const float og = fsigmoid(sg[2]);
    const float gt = ftanh(sg[3]);
    const float m = mask[b];
    const float c = c_in[i];
    float cn = fg * c + ig * gt;
    cn = cn * m + c * (1.f - m);
    const float h = h_in[i];
    float hn = og * ftanh(cn);
    hn = hn * m + h * (1.f - m);
    h_out[i] = hn;
    if (h_out2) h_out2[i] = hn;
    c_out[i] = cn;
    if (h_bf) h_bf[i] = f2bf(hn);
}

extern "C" void kernel_launch(void* const* d_in, const int* in_sizes, int n_in,
                              void* d_out, int out_size, void* d_ws, size_t ws_size,
                              hipStream_t stream) {
    const float* xt   = (const float*)d_in[0];
    const float* mask = (const float*)d_in[1];
    const float* V    = (const float*)d_in[2];
    const float* pos  = (const float*)d_in[3];
    const float* h1   = (const float*)d_in[4];
    const float* c1   = (const float*)d_in[5];
    const float* h2   = (const float*)d_in[6];
    const float* c2   = (const float*)d_in[7];
    const float* Wg   = (const float*)d_in[8];
    const float* bg   = (const float*)d_in[9];
    const float* Wi1  = (const float*)d_in[10];
    const float* bi1  = (const float*)d_in[11];
    const float* Wa1  = (const float*)d_in[12];
    const float* ba1  = (const float*)d_in[13];
    const float* Wh1  = (const float*)d_in[14];
    const float* bh1  = (const float*)d_in[15];
    const float* Wi2  = (const float*)d_in[16];
    const float* bi2  = (const float*)d_in[17];
    const float* Wa2  = (const float*)d_in[18];
    const float* ba2  = (const float*)d_in[19];
    const float* Wh2  = (const float*)d_in[20];
    const float* bh2  = (const float*)d_in[21];
    const float* Wv2a = (const float*)d_in[22];
    const float* bv2a = (const float*)d_in[23];
    const float* Wh2a = (const float*)d_in[24];
    const float* bh2a = (const float*)d_in[25];
    const float* Wa2w = (const float*)d_in[26];
    const float* ba2w = (const float*)d_in[27];

    float* out = (float*)d_out;
    float* out2  = out;
    float* out1  = out + (size_t)BB * RR;
    float* c1n   = out + 2 * (size_t)BB * RR;
    float* out2b = out + 3 * (size_t)BB * RR;
    float* c2n   = out + 4 * (size_t)BB * RR;

    // ---- workspace: bf16 region then fp32 region ----
    ushort* wsu = (ushort*)d_ws;
    size_t o = 0;
    ushort* Wh2aT0 = wsu + o; o += (size_t)512 * 1024;
    ushort* Wh2aT1 = wsu + o; o += (size_t)512 * 1024;
    ushort* WgT    = wsu + o; o += (size_t)1024 * 1024;
    ushort* Wv2aT  = wsu + o; o += (size_t)512 * 1024;
    ushort* Wi1T   = wsu + o; o += (size_t)4096 * 1024;
    ushort* Wa1T   = wsu + o; o += (size_t)4096 * 1024;
    ushort* Wh1T   = wsu + o; o += (size_t)4096 * 1024;
    ushort* Wi2T   = wsu + o; o += (size_t)4096 * 1024;
    ushort* Wa2T   = wsu + o; o += (size_t)4096 * 1024;
    ushort* Wh2T   = wsu + o; o += (size_t)4096 * 1024;
    ushort* xtb    = wsu + o; o += (size_t)1024 * 1024;
    ushort* h1b    = wsu + o; o += (size_t)1024 * 1024;
    ushort* h2b    = wsu + o; o += (size_t)1024 * 1024;
    ushort* gpb    = wsu + o; o += (size_t)1024 * 1024;
    ushort* afb    = wsu + o; o += (size_t)1024 * 1024;
    ushort* out1b  = wsu + o; o += (size_t)1024 * 1024;
    float* wsf   = (float*)(wsu + o);
    float* hqf   = wsf;                    // 1024*512
    float* partK = hqf + 524288;           // max 2*1024*4096 = 8M floats

    const dim3 blk(256);

    // ---- conversion / transpose passes ----
    {
        CP3 p; p.in[0] = xt; p.in[1] = h1; p.in[2] = h2;
        p.out[0] = xtb; p.out[1] = h1b; p.out[2] = h2b;
        conv_bf16_batch3_kernel<<<dim3(512, 3), blk, 0, stream>>>(p, 131072);
    }
    {
        TP6 p;
        p.in[0] = Wi1; p.in[1] = Wa1; p.in[2] = Wh1;
        p.in[3] = Wi2; p.in[4] = Wa2; p.in[5] = Wh2;
        p.out[0] = Wi1T; p.out[1] = Wa1T; p.out[2] = Wh1T;
        p.out[3] = Wi2T; p.out[4] = Wa2T; p.out[5] = Wh2T;
        for (int z = 0; z < 6; ++z) p.N[z] = 4096;
        transpose_conv_kernel<<<dim3(64, 16, 6), blk, 0, stream>>>(p);
    }
    {
        TP6 p;
        p.in[0] = Wh2a; p.in[1] = Wh2a + (size_t)1024 * 512;
        p.in[2] = Wg;   p.in[3] = Wv2a;
        p.out[0] = Wh2aT0; p.out[1] = Wh2aT1; p.out[2] = WgT; p.out[3] = Wv2aT;
        p.N[0] = 512; p.N[1] = 512; p.N[2] = 1024; p.N[3] = 512;
        p.in[4] = nullptr; p.in[5] = nullptr; p.out[4] = nullptr; p.out[5] = nullptr;
        p.N[4] = 0; p.N[5] = 0;
        transpose_conv_kernel<<<dim3(16, 16, 4), blk, 0, stream>>>(p);
    }

    // ---- hq = [h1,h2] @ Wh2a (split-K x8) + bias reduce ----
    gemm_bf16<2, 8><<<dim3(4, 8, 8), blk, 0, stream>>>(
        h1b, h2b, nullptr, Wh2aT0, Wh2aT1, nullptr, partK, 1024, 512);
    reduce_hq_kernel<<<dim3(2048), blk, 0, stream>>>(partK, bh2a, hqf);

    // ---- gate: xt @ Wg (split-K x4), fused relu*pos+pos -> bf16 ----
    gemm_bf16<1, 4><<<dim3(8, 8, 4), blk, 0, stream>>>(
        xtb, nullptr, nullptr, WgT, nullptr, nullptr, partK, 1024, 1024);
    reduce_gate_kernel<<<dim3(4096), blk, 0, stream>>>(partK, bg, pos, gpb);

    // ---- fused attention: GEMM + tanh-reduce + softmax + PV ----
    attn_fused_kernel<<<dim3(512), dim3(512), 0, stream>>>(
        V, Wv2aT, hqf, bv2a, Wa2w, ba2w, afb);

    // ---- LSTM layer 1 (split-K x2 over fused K = xt|gp|h1) ----
    gemm_bf16<3, 2><<<dim3(32, 8, 2), blk, 0, stream>>>(
        xtb, gpb, h1b, Wi1T, Wa1T, Wh1T, partK, 1024, 4096);
    lstm_finish2_kernel<<<dim3(4096), blk, 0, stream>>>(
        partK, bi1, ba1, bh1, c1, h1, mask, out1, nullptr, c1n, out1b);

    // ---- LSTM layer 2 (split-K x2 over fused K = out1|af|h2) ----
    gemm_bf16<3, 2><<<dim3(32, 8, 2), blk, 0, stream>>>(
        out1b, afb, h2b, Wi2T, Wa2T, Wh2T, partK, 1024, 4096);
    lstm_finish2_kernel<<<dim3(4096), blk, 0, stream>>>(
        partK, bi2, ba2, bh2, c2, h2, mask, out2, out2b, c2n, nullptr);
}

// Round 6
// 328.963 us; speedup vs baseline: 1.8938x; 1.8767x over previous
//
#include <hip/hip_runtime.h>
#include <math.h>

#define BB 1024
#define LL 40
#define RR 1024

using short8 = __attribute__((ext_vector_type(8))) short;
using us8    = __attribute__((ext_vector_type(8))) unsigned short;
using f32x4  = __attribute__((ext_vector_type(4))) float;

__device__ __forceinline__ ushort f2bf(float f) {
    union { float f; unsigned u; } a; a.f = f;
    unsigned r = a.u + 0x7fffu + ((a.u >> 16) & 1u);  // RNE
    return (ushort)(r >> 16);
}
__device__ __forceinline__ float bf2f(ushort u) {
    union { unsigned u; float f; } a; a.u = ((unsigned)u) << 16;
    return a.f;
}
__device__ __forceinline__ float ftanh(float x) {
    float cx = fminf(fmaxf(x, -15.f), 15.f);
    float e = __expf(2.f * cx);
    return (e - 1.f) / (e + 1.f);
}
__device__ __forceinline__ float fsigmoid(float x) {
    float cx = fminf(fmaxf(x, -30.f), 30.f);
    return 1.f / (1.f + __expf(-cx));
}

// async global -> LDS, 16 bytes per lane (m97's proven staging path)
__device__ __forceinline__ void gll16(const ushort* g, ushort* l) {
    __builtin_amdgcn_global_load_lds(
        (const __attribute__((address_space(1))) void*)g,
        (__attribute__((address_space(3))) void*)l,
        16, 0, 0);
}

// ---------------------------------------------------------------------------
// Flat fp32 -> bf16 convert (8 elems/thread)
// ---------------------------------------------------------------------------
__global__ __launch_bounds__(256) void conv_bf16_kernel(
    const float* __restrict__ src, ushort* __restrict__ dst, int n8)
{
    const int i = blockIdx.x * 256 + threadIdx.x;
    if (i >= n8) return;
    const float4* s4 = (const float4*)(src + (size_t)i * 8);
    float4 x = s4[0], y = s4[1];
    us8 v;
    v[0] = f2bf(x.x); v[1] = f2bf(x.y); v[2] = f2bf(x.z); v[3] = f2bf(x.w);
    v[4] = f2bf(y.x); v[5] = f2bf(y.y); v[6] = f2bf(y.z); v[7] = f2bf(y.w);
    ((us8*)dst)[i] = v;
}

struct CP3 { const float* in[3]; ushort* out[3]; };
__global__ __launch_bounds__(256) void conv_bf16_batch3_kernel(CP3 p, int n8)
{
    const int z = blockIdx.y;
    const int i = blockIdx.x * 256 + threadIdx.x;
    if (i >= n8) return;
    const float4* s4 = (const float4*)(p.in[z] + (size_t)i * 8);
    float4 x = s4[0], y = s4[1];
    us8 v;
    v[0] = f2bf(x.x); v[1] = f2bf(x.y); v[2] = f2bf(x.z); v[3] = f2bf(x.w);
    v[4] = f2bf(y.x); v[5] = f2bf(y.y); v[6] = f2bf(y.z); v[7] = f2bf(y.w);
    ((us8*)p.out[z])[i] = v;
}

// Transpose + convert: in fp32 [K=1024][N] -> out bf16 [N][1024].
struct TP6 { const float* in[6]; ushort* out[6]; int N[6]; };
__global__ __launch_bounds__(256) void transpose_conv_kernel(TP6 p)
{
    const int z = blockIdx.z;
    const int Nn = p.N[z];
    const int n0 = blockIdx.x * 64;
    if (n0 >= Nn) return;
    const int k0 = blockIdx.y * 64;
    const float* in = p.in[z];
    ushort* out = p.out[z];

    __shared__ float tile[64][65];
    const int t = threadIdx.x;
    const int tx = t & 63, ty = t >> 6;
#pragma unroll
    for (int r = 0; r < 16; ++r) {
        const int row = ty * 16 + r;
        tile[row][tx] = in[(size_t)(k0 + row) * Nn + n0 + tx];
    }
    __syncthreads();
    const int n = t >> 2, kq = t & 3;
    us8 v0, v1;
#pragma unroll
    for (int j = 0; j < 8; ++j) v0[j] = f2bf(tile[kq * 16 + j][n]);
#pragma unroll
    for (int j = 0; j < 8; ++j) v1[j] = f2bf(tile[kq * 16 + 8 + j][n]);
    ushort* op = out + (size_t)(n0 + n) * 1024 + k0 + kq * 16;
    *(us8*)op = v0;
    *((us8*)op + 1) = v1;
}

// ---------------------------------------------------------------------------
// m97-style BF16 MFMA GEMM: 128x128 tile, BK=32, 256 threads (4 waves),
// global_load_lds width-16 staging into linear [128][32] LDS, 2 barriers/step.
// A_p: bf16 [M][1024] row-major. W_p: bf16 [N][1024] (pre-transposed).
// C = sum_p A_p @ W_p^T. EPI: 2 = attn tanh-reduce, 3 = split-K partial store.
// ---------------------------------------------------------------------------
template <int NP, int SK, int EPI>
__global__ __launch_bounds__(256) void gemm_gl(
    const ushort* __restrict__ A0, const ushort* __restrict__ A1, const ushort* __restrict__ A2,
    const ushort* __restrict__ W0, const ushort* __restrict__ W1, const ushort* __restrict__ W2,
    float* __restrict__ C, int M, int N,
    const float* __restrict__ hq, const float* __restrict__ bv2a,
    const float* __restrict__ Wa2w, float* __restrict__ epart)
{
    __shared__ ushort As[128 * 32];   // [row][k] linear, 8 KB
    __shared__ ushort Bs[128 * 32];   // [col][k] linear, 8 KB

    const int t = threadIdx.x, lane = t & 63, wave = t >> 6;
    const int wm = wave >> 1, wn = wave & 1;

    int bx, by;
    if constexpr (EPI == 2) {
        // XCD-chunked bijective swizzle: nwg = 4*320 = 1280 = 8*160
        const int lin = blockIdx.y * gridDim.x + blockIdx.x;
        const int swz = (lin & 7) * 160 + (lin >> 3);
        bx = swz & 3; by = swz >> 2;
    } else { bx = blockIdx.x; by = blockIdx.y; }
    const int m0 = by * 128, n0 = bx * 128;

    // staging decomposition: load j in {0,1} covers rows 64j..64j+63;
    // within wave: row = 64j + 16*wave + (lane>>2), kq = lane&3 (8 elems = 16B)
    const int srow = 16 * wave + (lane >> 2);
    const int skq  = lane & 3;

    f32x4 acc[4][4];
#pragma unroll
    for (int i = 0; i < 4; ++i)
#pragma unroll
        for (int j = 0; j < 4; ++j) acc[i][j] = (f32x4){0.f, 0.f, 0.f, 0.f};

    const int total = NP * 32;           // K-steps of 32
    const int per   = total / SK;
    const int s0v   = blockIdx.z * per;
    const int sEnd  = s0v + per;

    for (int s = s0v; s < sEnd; ++s) {
        const int p  = (NP == 1) ? 0 : (s >> 5);
        const int k0 = (s & 31) << 5;
        const ushort* Ap = (p == 0) ? A0 : ((p == 1) ? A1 : A2);
        const ushort* Wp = (p == 0) ? W0 : ((p == 1) ? W1 : W2);
        const ushort* ga = Ap + (size_t)(m0 + srow) * 1024 + k0 + skq * 8;
        const ushort* gb = Wp + (size_t)(n0 + srow) * 1024 + k0 + skq * 8;
        gll16(ga,                 &As[512 * wave]);
        gll16(ga + 64 * 1024,     &As[2048 + 512 * wave]);
        gll16(gb,                 &Bs[512 * wave]);
        gll16(gb + 64 * 1024,     &Bs[2048 + 512 * wave]);
        __syncthreads();   // drains vmcnt(0): tiles resident

        short8 aF[4], bF[4];
#pragma unroll
        for (int mi = 0; mi < 4; ++mi)
            aF[mi] = *(const short8*)&As[(wm * 64 + mi * 16 + (lane & 15)) * 32 + (lane >> 4) * 8];
#pragma unroll
        for (int ni = 0; ni < 4; ++ni)
            bF[ni] = *(const short8*)&Bs[(wn * 64 + ni * 16 + (lane & 15)) * 32 + (lane >> 4) * 8];
#pragma unroll
        for (int mi = 0; mi < 4; ++mi)
#pragma unroll
            for (int ni = 0; ni < 4; ++ni)
                acc[mi][ni] = __builtin_amdgcn_mfma_f32_16x16x32_bf16(aF[mi], bF[ni], acc[mi][ni], 0, 0, 0);
        __syncthreads();   // safe to overwrite LDS next step
    }

    if constexpr (EPI == 3) {
        float* Cz = C + (size_t)blockIdx.z * M * N;
#pragma unroll
        for (int ni = 0; ni < 4; ++ni) {
            const int col = n0 + wn * 64 + ni * 16 + (lane & 15);
#pragma unroll
            for (int mi = 0; mi < 4; ++mi) {
                const int row = m0 + wm * 64 + mi * 16 + ((lane >> 4) << 2);
#pragma unroll
                for (int r = 0; r < 4; ++r)
                    Cz[(size_t)(row + r) * N + col] = acc[mi][ni][r];
            }
        }
    } else if constexpr (EPI == 2) {
        // tanh(acc + hq + bv2a) * Wa2w, reduced over this block's 128 cols
        float* red = (float*)As;           // [128][2], LDS reuse after final barrier
        float wa[4], bv[4];
        int coln[4];
#pragma unroll
        for (int ni = 0; ni < 4; ++ni) {
            coln[ni] = n0 + wn * 64 + ni * 16 + (lane & 15);
            wa[ni] = Wa2w[coln[ni]];
            bv[ni] = bv2a[coln[ni]];
        }
#pragma unroll
        for (int mi = 0; mi < 4; ++mi) {
            const int rowl = wm * 64 + mi * 16 + ((lane >> 4) << 2);
#pragma unroll
            for (int r = 0; r < 4; ++r) {
                const int row = m0 + rowl + r;
                const int b = row / LL;
                float v = 0.f;
#pragma unroll
                for (int ni = 0; ni < 4; ++ni) {
                    float x = acc[mi][ni][r] + hq[(size_t)b * 512 + coln[ni]] + bv[ni];
                    v += ftanh(x) * wa[ni];
                }
                v += __shfl_xor(v, 1);
                v += __shfl_xor(v, 2);
                v += __shfl_xor(v, 4);
                v += __shfl_xor(v, 8);
                if ((lane & 15) == 0) red[(rowl + r) * 2 + wn] = v;
            }
        }
        __syncthreads();
        if (t < 128)
            epart[(size_t)(m0 + t) * 4 + bx] = red[t * 2] + red[t * 2 + 1];
    }
}

// ---------------------------------------------------------------------------
__global__ __launch_bounds__(256) void reduce_hq_kernel(
    const float* __restrict__ part, const float* __restrict__ bias, float* __restrict__ hq)
{
    const int i = blockIdx.x * 256 + threadIdx.x;   // < 1024*512
    float s = bias[i & 511];
#pragma unroll
    for (int z = 0; z < 8; ++z) s += part[(size_t)z * 524288 + i];
    hq[i] = s;
}

__global__ __launch_bounds__(256) void reduce_gate_kernel(
    const float* __restrict__ part, const float* __restrict__ bias,
    const float* __restrict__ pos, ushort* __restrict__ gpb)
{
    const int i = blockIdx.x * 256 + threadIdx.x;   // < 1024*1024
    float s = bias[i & 1023];
#pragma unroll
    for (int z = 0; z < 4; ++z) s += part[(size_t)z * 1048576 + i];
    const float g = fmaxf(s, 0.f);
    gpb[i] = f2bf(g * pos[i] + pos[i]);
}

// ---------------------------------------------------------------------------
// Per-batch softmax over L + weighted sum over bf16 V. Writes bf16 af.
// ---------------------------------------------------------------------------
__global__ __launch_bounds__(256) void softmax_af_kernel(
    const float* __restrict__ epart, const ushort* __restrict__ Vb,
    const float* __restrict__ ba2w, ushort* __restrict__ afb)
{
    const int b = blockIdx.x;
    const int tid = threadIdx.x;
    __shared__ float e_raw[LL];
    __shared__ float e_exp[LL];

    if (tid < LL) {
        const float* ep = &epart[(size_t)(b * LL + tid) * 4];
        float e = ba2w[0];
#pragma unroll
        for (int c = 0; c < 4; ++c) e += ep[c];
        e_raw[tid] = e;
    }
    __syncthreads();
    float mx = -1e30f;
#pragma unroll
    for (int l = 0; l < LL; ++l) mx = fmaxf(mx, e_raw[l]);
    if (tid < LL) e_exp[tid] = __expf(e_raw[tid] - mx);
    __syncthreads();
    float sum = 0.f;
#pragma unroll
    for (int l = 0; l < LL; ++l) sum += e_exp[l];
    const float inv = 1.f / sum;

    const int r4 = tid * 4;
    const ushort* vp = &Vb[(size_t)b * LL * RR + r4];
    float a0 = 0.f, a1 = 0.f, a2 = 0.f, a3 = 0.f;
#pragma unroll 8
    for (int l = 0; l < LL; ++l) {
        ushort4 v = *(const ushort4*)&vp[(size_t)l * RR];
        const float w = e_exp[l];
        a0 += w * bf2f(v.x); a1 += w * bf2f(v.y);
        a2 += w * bf2f(v.z); a3 += w * bf2f(v.w);
    }
    ushort* op = &afb[(size_t)b * RR + r4];
    op[0] = f2bf(a0 * inv); op[1] = f2bf(a1 * inv);
    op[2] = f2bf(a2 * inv); op[3] = f2bf(a3 * inv);
}

// ---------------------------------------------------------------------------
// LSTM epilogue: sum 4 split-K partials + 3 biases, gates, mask blend.
// ---------------------------------------------------------------------------
__global__ __launch_bounds__(256) void lstm_finish4_kernel(
    const float* __restrict__ part,
    const float* __restrict__ bi, const float* __restrict__ ba, const float* __restrict__ bh,
    const float* __restrict__ c_in, const float* __restrict__ h_in, const float* __restrict__ mask,
    float* __restrict__ h_out, float* __restrict__ h_out2,
    float* __restrict__ c_out, ushort* __restrict__ h_bf)
{
    const int i = blockIdx.x * 256 + threadIdx.x;  // [0, B*R)
    const int b = i >> 10;
    const int r = i & 1023;
    float sg[4];
#pragma unroll
    for (int g = 0; g < 4; ++g) {
        const int gr = g * 1024 + r;
        float s = bi[gr] + ba[gr] + bh[gr];
#pragma unroll
        for (int z = 0; z < 4; ++z)
            s += part[(size_t)z * 4194304 + (size_t)b * 4096 + gr];
        sg[g] = s;
    }
    const float ig = fsigmoid(sg[0]);
    const float fg = fsigmoid(sg[1]);
    const float og = fsigmoid(sg[2]);
    const float gt = ftanh(sg[3]);
    const float m = mask[b];
    const float c = c_in[i];
    float cn = fg * c + ig * gt;
    cn = cn * m + c * (1.f - m);
    const float h = h_in[i];
    float hn = og * ftanh(cn);
    hn = hn * m + h * (1.f - m);
    h_out[i] = hn;
    if (h_out2) h_out2[i] = hn;
    c_out[i] = cn;
    if (h_bf) h_bf[i] = f2bf(hn);
}

extern "C" void kernel_launch(void* const* d_in, const int* in_sizes, int n_in,
                              void* d_out, int out_size, void* d_ws, size_t ws_size,
                              hipStream_t stream) {
    const float* xt   = (const float*)d_in[0];
    const float* mask = (const float*)d_in[1];
    const float* V    = (const float*)d_in[2];
    const float* pos  = (const float*)d_in[3];
    const float* h1   = (const float*)d_in[4];
    const float* c1   = (const float*)d_in[5];
    const float* h2   = (const float*)d_in[6];
    const float* c2   = (const float*)d_in[7];
    const float* Wg   = (const float*)d_in[8];
    const float* bg   = (const float*)d_in[9];
    const float* Wi1  = (const float*)d_in[10];
    const float* bi1  = (const float*)d_in[11];
    const float* Wa1  = (const float*)d_in[12];
    const float* ba1  = (const float*)d_in[13];
    const float* Wh1  = (const float*)d_in[14];
    const float* bh1  = (const float*)d_in[15];
    const float* Wi2  = (const float*)d_in[16];
    const float* bi2  = (const float*)d_in[17];
    const float* Wa2  = (const float*)d_in[18];
    const float* ba2  = (const float*)d_in[19];
    const float* Wh2  = (const float*)d_in[20];
    const float* bh2  = (const float*)d_in[21];
    const float* Wv2a = (const float*)d_in[22];
    const float* bv2a = (const float*)d_in[23];
    const float* Wh2a = (const float*)d_in[24];
    const float* bh2a = (const float*)d_in[25];
    const float* Wa2w = (const float*)d_in[26];
    const float* ba2w = (const float*)d_in[27];

    float* out = (float*)d_out;
    float* out2  = out;
    float* out1  = out + (size_t)BB * RR;
    float* c1n   = out + 2 * (size_t)BB * RR;
    float* out2b = out + 3 * (size_t)BB * RR;
    float* c2n   = out + 4 * (size_t)BB * RR;

    // ---- workspace: bf16 region then fp32 region ----
    ushort* wsu = (ushort*)d_ws;
    size_t o = 0;
    ushort* Vb     = wsu + o; o += (size_t)40960 * 1024;   // 41.9M elems
    ushort* Wh2aT0 = wsu + o; o += (size_t)512 * 1024;
    ushort* Wh2aT1 = wsu + o; o += (size_t)512 * 1024;
    ushort* WgT    = wsu + o; o += (size_t)1024 * 1024;
    ushort* Wv2aT  = wsu + o; o += (size_t)512 * 1024;
    ushort* Wi1T   = wsu + o; o += (size_t)4096 * 1024;
    ushort* Wa1T   = wsu + o; o += (size_t)4096 * 1024;
    ushort* Wh1T   = wsu + o; o += (size_t)4096 * 1024;
    ushort* Wi2T   = wsu + o; o += (size_t)4096 * 1024;
    ushort* Wa2T   = wsu + o; o += (size_t)4096 * 1024;
    ushort* Wh2T   = wsu + o; o += (size_t)4096 * 1024;
    ushort* xtb    = wsu + o; o += (size_t)1024 * 1024;
    ushort* h1b    = wsu + o; o += (size_t)1024 * 1024;
    ushort* h2b    = wsu + o; o += (size_t)1024 * 1024;
    ushort* gpb    = wsu + o; o += (size_t)1024 * 1024;
    ushort* afb    = wsu + o; o += (size_t)1024 * 1024;
    ushort* out1b  = wsu + o; o += (size_t)1024 * 1024;
    float* wsf    = (float*)(wsu + o);
    float* hqf    = wsf;                   // 524288
    float* epart  = hqf + 524288;          // 40960*4
    float* partSm = epart + 163840;        // 4.19M floats (hq x8 / gate x4 partials)
    // LSTM split-K partials (4 x 1024 x 4096 = 16.8M floats) alias Vb,
    // which is dead once softmax_af has run.
    float* partK  = (float*)Vb;

    const dim3 blk(256);

    // ---- conversion / transpose passes ----
    conv_bf16_kernel<<<dim3(20480), blk, 0, stream>>>(V, Vb, 5242880);
    {
        CP3 p; p.in[0] = xt; p.in[1] = h1; p.in[2] = h2;
        p.out[0] = xtb; p.out[1] = h1b; p.out[2] = h2b;
        conv_bf16_batch3_kernel<<<dim3(512, 3), blk, 0, stream>>>(p, 131072);
    }
    {
        TP6 p;
        p.in[0] = Wi1; p.in[1] = Wa1; p.in[2] = Wh1;
        p.in[3] = Wi2; p.in[4] = Wa2; p.in[5] = Wh2;
        p.out[0] = Wi1T; p.out[1] = Wa1T; p.out[2] = Wh1T;
        p.out[3] = Wi2T; p.out[4] = Wa2T; p.out[5] = Wh2T;
        for (int z = 0; z < 6; ++z) p.N[z] = 4096;
        transpose_conv_kernel<<<dim3(64, 16, 6), blk, 0, stream>>>(p);
    }
    {
        TP6 p;
        p.in[0] = Wh2a; p.in[1] = Wh2a + (size_t)1024 * 512;
        p.in[2] = Wg;   p.in[3] = Wv2a;
        p.out[0] = Wh2aT0; p.out[1] = Wh2aT1; p.out[2] = WgT; p.out[3] = Wv2aT;
        p.N[0] = 512; p.N[1] = 512; p.N[2] = 1024; p.N[3] = 512;
        p.in[4] = nullptr; p.in[5] = nullptr; p.out[4] = nullptr; p.out[5] = nullptr;
        p.N[4] = 0; p.N[5] = 0;
        transpose_conv_kernel<<<dim3(16, 16, 4), blk, 0, stream>>>(p);
    }

    // ---- hq = [h1,h2] @ Wh2a (split-K x8) + bias reduce ----
    gemm_gl<2, 8, 3><<<dim3(4, 8, 8), blk, 0, stream>>>(
        h1b, h2b, nullptr, Wh2aT0, Wh2aT1, nullptr,
        partSm, 1024, 512, nullptr, nullptr, nullptr, nullptr);
    reduce_hq_kernel<<<dim3(2048), blk, 0, stream>>>(partSm, bh2a, hqf);

    // ---- gate: xt @ Wg (split-K x4), fused relu*pos+pos -> bf16 ----
    gemm_gl<1, 4, 3><<<dim3(8, 8, 4), blk, 0, stream>>>(
        xtb, nullptr, nullptr, WgT, nullptr, nullptr,
        partSm, 1024, 1024, nullptr, nullptr, nullptr, nullptr);
    reduce_gate_kernel<<<dim3(4096), blk, 0, stream>>>(partSm, bg, pos, gpb);

    // ---- attention scores: Vb @ Wv2a, fused tanh-reduce -> epart ----
    gemm_gl<1, 1, 2><<<dim3(4, 320, 1), blk, 0, stream>>>(
        Vb, nullptr, nullptr, Wv2aT, nullptr, nullptr,
        nullptr, 40960, 512, hqf, bv2a, Wa2w, epart);
    softmax_af_kernel<<<dim3(BB), blk, 0, stream>>>(epart, Vb, ba2w, afb);

    // ---- LSTM layer 1 (split-K x4 over fused K = xt|gp|h1) ----
    gemm_gl<3, 4, 3><<<dim3(32, 8, 4), blk, 0, stream>>>(
        xtb, gpb, h1b, Wi1T, Wa1T, Wh1T,
        partK, 1024, 4096, nullptr, nullptr, nullptr, nullptr);
    lstm_finish4_kernel<<<dim3(4096), blk, 0, stream>>>(
        partK, bi1, ba1, bh1, c1, h1, mask, out1, nullptr, c1n, out1b);

    // ---- LSTM layer 2 (split-K x4 over fused K = out1|af|h2) ----
    gemm_gl<3, 4, 3><<<dim3(32, 8, 4), blk, 0, stream>>>(
        out1b, afb, h2b, Wi2T, Wa2T, Wh2T,
        partK, 1024, 4096, nullptr, nullptr, nullptr, nullptr);
    lstm_finish4_kernel<<<dim3(4096), blk, 0, stream>>>(
        partK, bi2, ba2, bh2, c2, h2, mask, out2, out2b, c2n, nullptr);
}